// Round 14
// baseline (201.053 us; speedup 1.0000x reference)
//
#include <hip/hip_runtime.h>
#include <stddef.h>

#define B_ 2
#define L_ 384
#define D_ 1024
#define K_ 128
#define H_ 32

#define MINV (-3.402823466e38f)
// Exported -inf sentinel: must stay FINITE after bf16 rounding (bf16 max ~3.39e38).
#define NEG_BIG (-1.0e38f)
#define SCALING_ 0.08838834764831845f
#define INV_SQRT_2PI 0.3989422804014327f

typedef __attribute__((ext_vector_type(8))) short bf16x8;
typedef __attribute__((ext_vector_type(4))) float f32x4;

__device__ __forceinline__ float finitize(float x) {
    return fminf(fmaxf(x, -1.0e38f), 1.0e38f);
}
__device__ __forceinline__ unsigned short f2bf(float x) {
    unsigned int u = __float_as_uint(x);
    u += 0x7FFFu + ((u >> 16) & 1u);
    return (unsigned short)(u >> 16);
}
__device__ __forceinline__ unsigned short f2bf_rtz(float x) {
    return (unsigned short)(__float_as_uint(x) >> 16);
}
// tanh-form gelu: max abs err ~3e-4, 1 exp + 1 rcp  (R8 original — best measured)
__device__ __forceinline__ float gelu_tanh(float x) {
    const float x2 = x * x;
    const float z = x * fmaf(0.0356774081f, x2, 0.7978845608f);
    const float e = __expf(2.0f * z);
    const float t = fmaf(-2.0f, __builtin_amdgcn_rcpf(e + 1.0f), 1.0f);
    const float hx = 0.5f * x;
    return fmaf(hx, t, hx);
}
// convert 8 consecutive f32 to a bf16x8 fragment (same f2bf rounding as prep)
__device__ __forceinline__ bf16x8 cvt8(const float* __restrict__ src) {
    const float4 a = *(const float4*)src;
    const float4 b = *(const float4*)(src + 4);
    bf16x8 r;
    r[0] = (short)f2bf(a.x); r[1] = (short)f2bf(a.y);
    r[2] = (short)f2bf(a.z); r[3] = (short)f2bf(a.w);
    r[4] = (short)f2bf(b.x); r[5] = (short)f2bf(b.y);
    r[6] = (short)f2bf(b.z); r[7] = (short)f2bf(b.w);
    return r;
}

// ---------------------------------------------------------------------------
// time-MLP GEMM body (ts1), R15: A (sinusoidal features) synthesized
// IN-REGISTER during staging — identical formula+rounding to the old
// prep_sin (exp/sin/cos then f2bf), so h1 is bit-identical. Removes the
// sin_bf dependency. B (Wt1 f32) register-prefetched as before.
// smem: sA[32][72] us @0 (4608 B), sB[64][72] us @4608 (9216 B) = 13824 B
// ---------------------------------------------------------------------------
__device__ __forceinline__ void gemm_ts_body(
    char* smem, int m0, int n0,
    const float* __restrict__ time_step, const unsigned char* __restrict__ clean,
    const float* __restrict__ Bw,
    const float* __restrict__ bias, unsigned short* __restrict__ Cbf,
    int N, int Kd)
{
    unsigned short (*sA)[72] = (unsigned short(*)[72])smem;
    unsigned short (*sB)[72] = (unsigned short(*)[72])(smem + 4608);
    const int tid  = threadIdx.x;
    const int lane = tid & 63;
    const int wave = tid >> 6;
    const int l15  = lane & 15;
    const int quad = lane >> 4;
    const int mt   = wave & 1;
    const int np   = wave >> 1;

    const int ar = tid >> 3, ac = (tid & 7) * 8;
    const int bc4 = (tid & 15) * 4;

    const int arow = m0 + ar;
    const float t = (clean[arow] ? 0.0f : time_step[arow]) * 1000.0f;

    f32x4 acc[2];
#pragma unroll
    for (int t2 = 0; t2 < 2; ++t2) acc[t2] = (f32x4){0.f, 0.f, 0.f, 0.f};

    float4 rbv[4];
#pragma unroll
    for (int c = 0; c < 4; ++c)
        rbv[c] = *(const float4*)&Bw[(size_t)(n0 + ((tid + c * 256) >> 4)) * Kd + bc4];

    for (int k0 = 0; k0 < Kd; k0 += 64) {
        // synthesize A elements k0+ac .. +7 (run never crosses the 512 split)
        {
            const int kbase = k0 + ac;
            ushort4 p0, p1;
#pragma unroll
            for (int e = 0; e < 8; ++e) {
                const int k = kbase + e;
                const int km = (k < 512) ? k : (k - 512);
                const float f = __expf(-9.210340371976184f * (float)km * (1.0f / 512.0f));
                const float ang = t * f;
                const float v = (k < 512) ? __sinf(ang) : __cosf(ang);
                if (e < 4) ((unsigned short*)&p0)[e] = f2bf(v);
                else       ((unsigned short*)&p1)[e - 4] = f2bf(v);
            }
            *(ushort4*)&sA[ar][ac]     = p0;
            *(ushort4*)&sA[ar][ac + 4] = p1;
        }
#pragma unroll
        for (int c = 0; c < 4; ++c) {
            ushort4 p;
            p.x = f2bf(rbv[c].x); p.y = f2bf(rbv[c].y);
            p.z = f2bf(rbv[c].z); p.w = f2bf(rbv[c].w);
            *(ushort4*)&sB[(tid + c * 256) >> 4][bc4] = p;
        }
        __syncthreads();
        if (k0 + 64 < Kd) {
#pragma unroll
            for (int c = 0; c < 4; ++c)
                rbv[c] = *(const float4*)&Bw[(size_t)(n0 + ((tid + c * 256) >> 4)) * Kd + k0 + 64 + bc4];
        }
#pragma unroll
        for (int kk = 0; kk < 64; kk += 32) {
            const bf16x8 av = *(const bf16x8*)&sA[mt * 16 + l15][kk + quad * 8];
#pragma unroll
            for (int t2 = 0; t2 < 2; ++t2) {
                const bf16x8 bv = *(const bf16x8*)&sB[(np * 2 + t2) * 16 + l15][kk + quad * 8];
                acc[t2] = __builtin_amdgcn_mfma_f32_16x16x32_bf16(av, bv, acc[t2], 0, 0, 0);
            }
        }
        __syncthreads();
    }
#pragma unroll
    for (int t2 = 0; t2 < 2; ++t2) {
        const int nc = n0 + (np * 2 + t2) * 16 + l15;
        const float bv = bias[nc];
#pragma unroll
        for (int r = 0; r < 4; ++r) {
            const int mr = m0 + mt * 16 + quad * 4 + r;
            float v = acc[t2][r] + bv;
            v = v / (1.0f + __expf(-v));
            Cbf[(size_t)mr * N + nc] = f2bf(v);
        }
    }
}

// ---------------------------------------------------------------------------
// Edge body — EXACT R8 structure (best measured: 61-63 µs), except W1/W2
// fragments now converted inline from f32 (same f2bf rounding; 80 KB via
// L2) — removes the prep dependency. padout written here too.
// smem pool (34816 B): sEF@0 [2][32][136]us, sACT@17408 [32][136]us,
// sGab@26112 [32][33]f, sD@30336 [384]f, sRed@31872 [256]f,
// sYall@32896 [384]f, sPadCol@34432 [384]uc
// ---------------------------------------------------------------------------
__device__ __forceinline__ void edge_body(
    char* smem, int row,
    const int* __restrict__ token_id,
    const unsigned char* __restrict__ is_periodic,
    const float* __restrict__ pos,
    const unsigned char* __restrict__ adj,
    const int* __restrict__ nte,
    const float* __restrict__ gbf_means,
    const float* __restrict__ gbf_stds,
    const float* __restrict__ gbf_mul,
    const float* __restrict__ gbf_bias,
    const float* __restrict__ b1,
    const float* __restrict__ b2,
    const float* __restrict__ Wpos,
    const float* __restrict__ W1,
    const float* __restrict__ W2,
    unsigned short* __restrict__ pfe_bf,
    unsigned short* __restrict__ ef_bf,
    float* __restrict__ out_pab,
    float* __restrict__ out_pad)
{
    const int b = row / L_;
    const int i = row - b * L_;
    const int tid = threadIdx.x;

    const int tok_i = token_id[row];
    if (tid == 0) out_pad[row] = (tok_i == 0) ? 1.0f : 0.0f;
    if (tok_i == 0) {
        for (int idx = tid; idx < H_ * L_; idx += 256) {
            const int h = idx / L_;
            const int j = idx - h * L_;
            out_pab[((size_t)(b * H_ + h) * L_ + i) * L_ + j] = 0.0f;
        }
        if (tid < K_) {
            pfe_bf[(size_t)row * K_ + tid] = 0;
            ef_bf[(size_t)row * K_ + tid]  = 0;
        }
        return;
    }

    typedef unsigned short efbuf_t[32][136];
    efbuf_t* sEF = (efbuf_t*)smem;
    unsigned short (*sACT)[136] = (unsigned short(*)[136])(smem + 17408);
    float (*sGab)[33] = (float(*)[33])(smem + 26112);
    float* sD      = (float*)(smem + 30336);
    float* sRed    = (float*)(smem + 31872);
    float* sYall   = (float*)(smem + 32896);
    unsigned char* sPadCol = (unsigned char*)(smem + 34432);

    for (int j = tid; j < L_; j += 256)
        sPadCol[j] = (token_id[b * L_ + j] == 0) ? 1 : 0;

    const float px = pos[(size_t)row * 3 + 0];
    const float py = pos[(size_t)row * 3 + 1];
    const float pz = pos[(size_t)row * 3 + 2];
    for (int jg2 = tid; jg2 < L_; jg2 += 256) {
        const float dx = px - pos[(size_t)(b * L_ + jg2) * 3 + 0];
        const float dy = py - pos[(size_t)(b * L_ + jg2) * 3 + 1];
        const float dz = pz - pos[(size_t)(b * L_ + jg2) * 3 + 2];
        const float dist = sqrtf(fmaxf(dx * dx + dy * dy + dz * dz, 1e-12f));
        const size_t eoff = ((size_t)(b * L_ + i) * L_ + jg2) * 2;
        const int e0 = nte[eoff], e1 = nte[eoff + 1];
        sYall[jg2] = (gbf_mul[e0] + gbf_mul[e1]) * dist + (gbf_bias[e0] + gbf_bias[e1]);
    }

    const int lane = tid & 63;
    const int wave = tid >> 6;
    const int l15  = lane & 15;
    const int quad = lane >> 4;
    const int mt   = wave & 1;
    const int ntb  = (wave >> 1) * 4;
    float rb1[4];
#pragma unroll
    for (int nt = 0; nt < 4; ++nt) rb1[nt] = b1[(ntb + nt) * 16 + l15];
    const int hc = (wave >> 1) * 16 + l15;
    const float rb2 = b2[hc];
    bf16x8 w1f[4][4];
#pragma unroll
    for (int ks = 0; ks < 4; ++ks)
#pragma unroll
        for (int nt = 0; nt < 4; ++nt)
            w1f[ks][nt] = cvt8(&W1[(size_t)((ntb + nt) * 16 + l15) * K_ + ks * 32 + quad * 8]);
    bf16x8 bv2[4];
#pragma unroll
    for (int ks = 0; ks < 4; ++ks)
        bv2[ks] = cvt8(&W2[(size_t)hc * K_ + ks * 32 + quad * 8]);

    const int kg4 = (tid & 31) * 4;
    const int jg  = tid >> 5;
    const int jb  = jg * 4;
    float meanv[4], istdv[4], cKv[4];
#pragma unroll
    for (int c = 0; c < 4; ++c) {
        meanv[c] = gbf_means[kg4 + c];
        const float s = fabsf(gbf_stds[kg4 + c]) + 1e-5f;
        istdv[c] = 1.0f / s;
        cKv[c]   = INV_SQRT_2PI * istdv[c];
    }
    float efs[4] = {0.f, 0.f, 0.f, 0.f};

    __syncthreads();

#pragma unroll
    for (int jj = 0; jj < 4; ++jj) {
        const int j = jb + jj;
        const float y = sYall[j];
        const bool ok = !sPadCol[j];
        ushort4 p;
#pragma unroll
        for (int c = 0; c < 4; ++c) {
            const float a = (y - meanv[c]) * istdv[c];
            const float ef = __expf(-0.5f * a * a) * cKv[c];
            ((unsigned short*)&p)[c] = f2bf_rtz(ef);
            if (ok) efs[c] += ef;
        }
        *(ushort4*)&sEF[0][j][kg4] = p;
    }
    __syncthreads();

    for (int tile = 0; tile < L_ / 32; ++tile) {
        const int jt0 = tile * 32;
        const int cur = tile & 1, nxt = cur ^ 1;

        f32x4 acc1[4];
#pragma unroll
        for (int nt = 0; nt < 4; ++nt) acc1[nt] = (f32x4){0.f, 0.f, 0.f, 0.f};
#pragma unroll
        for (int ks = 0; ks < 4; ++ks) {
            const bf16x8 av = *(const bf16x8*)&sEF[cur][mt * 16 + l15][ks * 32 + quad * 8];
#pragma unroll
            for (int nt = 0; nt < 4; ++nt)
                acc1[nt] = __builtin_amdgcn_mfma_f32_16x16x32_bf16(av, w1f[ks][nt], acc1[nt], 0, 0, 0);
        }

        if (tile + 1 < L_ / 32) {
            const int jn0 = jt0 + 32;
#pragma unroll
            for (int jj = 0; jj < 4; ++jj) {
                const int j = jb + jj;
                const float y = sYall[jn0 + j];
                const bool ok = !sPadCol[jn0 + j];
                ushort4 p;
#pragma unroll
                for (int c = 0; c < 4; ++c) {
                    const float a = (y - meanv[c]) * istdv[c];
                    const float ef = __expf(-0.5f * a * a) * cKv[c];
                    ((unsigned short*)&p)[c] = f2bf_rtz(ef);
                    if (ok) efs[c] += ef;
                }
                *(ushort4*)&sEF[nxt][j][kg4] = p;
            }
        }

#pragma unroll
        for (int nt = 0; nt < 4; ++nt) {
            const int kkc = (ntb + nt) * 16 + l15;
#pragma unroll
            for (int r = 0; r < 4; ++r) {
                const float v = gelu_tanh(acc1[nt][r] + rb1[nt]);
                sACT[mt * 16 + quad * 4 + r][kkc] = f2bf_rtz(v);
            }
        }
        __syncthreads();   // A

        f32x4 acc2 = (f32x4){0.f, 0.f, 0.f, 0.f};
#pragma unroll
        for (int ks = 0; ks < 4; ++ks) {
            const bf16x8 av = *(const bf16x8*)&sACT[mt * 16 + l15][ks * 32 + quad * 8];
            acc2 = __builtin_amdgcn_mfma_f32_16x16x32_bf16(av, bv2[ks], acc2, 0, 0, 0);
        }
        const int jl0 = mt * 16 + quad * 4;
#pragma unroll
        for (int r = 0; r < 4; ++r) sGab[jl0 + r][hc] = acc2[r] + rb2;
        __syncthreads();   // B

        {
            const int h = tid >> 3, f = tid & 7;
            const int jb2 = f * 4;
            float4 st;
#pragma unroll
            for (int r = 0; r < 4; ++r) {
                float v = finitize(sGab[jb2 + r][h]);
                if (sPadCol[jt0 + jb2 + r]) v = NEG_BIG;
                ((float*)&st)[r] = v;
            }
            *(float4*)&out_pab[((size_t)(b * H_ + h) * L_ + i) * L_ + jt0 + jb2] = st;
        }
        if (tid < 32) {
            float s = 0.0f;
#pragma unroll
            for (int h = 0; h < 32; ++h) s += sGab[tid][h];
            sD[jt0 + tid] = s;
        }
    }

    {
        float* efScr = (float*)sACT;
#pragma unroll
        for (int c = 0; c < 4; ++c) efScr[jg * 128 + kg4 + c] = efs[c];
    }
    __syncthreads();
    if (tid < 128) {
        const float* efScr = (const float*)sACT;
        float s = 0.0f;
#pragma unroll
        for (int g = 0; g < 8; ++g) s += efScr[g * 128 + tid];
        ef_bf[(size_t)row * K_ + tid] = f2bf(s);
    }
    __syncthreads();

    const bool molecule = (tok_i <= 129) && (is_periodic[b] == 0);
    float lmax = -INFINITY;
    for (int j = tid; j < L_; j += 256) {
        const bool colpad = sPadCol[j] != 0;
        const bool adj_eff = (adj[((size_t)(b * L_ + i)) * L_ + j] != 0) || (!molecule);
        const float dv = (colpad || !adj_eff) ? MINV : sD[j];
        const float s = dv * SCALING_;
        sD[j] = s;
        lmax = fmaxf(lmax, s);
    }
#pragma unroll
    for (int off = 32; off > 0; off >>= 1) lmax = fmaxf(lmax, __shfl_xor(lmax, off));
    if (lane == 0) sRed[wave] = lmax;
    __syncthreads();
    const float smax = fmaxf(fmaxf(sRed[0], sRed[1]), fmaxf(sRed[2], sRed[3]));
    float lsum = 0.0f;
    for (int j = tid; j < L_; j += 256) {
        const float e = __expf(sD[j] - smax);
        sD[j] = e;
        lsum += e;
    }
#pragma unroll
    for (int off = 32; off > 0; off >>= 1) lsum += __shfl_xor(lsum, off);
    if (lane == 0) sRed[4 + wave] = lsum;
    __syncthreads();
    const float inv = 1.0f / (sRed[4] + sRed[5] + sRed[6] + sRed[7]);

    float a0 = 0.f, a1 = 0.f, a2 = 0.f;
    for (int j = tid; j < L_; j += 256) {
        if (!sPadCol[j]) {
            const float e = sD[j];
            a0 += e * pos[(size_t)(b * L_ + j) * 3 + 0];
            a1 += e * pos[(size_t)(b * L_ + j) * 3 + 1];
            a2 += e * pos[(size_t)(b * L_ + j) * 3 + 2];
        }
    }
#pragma unroll
    for (int off = 32; off > 0; off >>= 1) {
        a0 += __shfl_xor(a0, off);
        a1 += __shfl_xor(a1, off);
        a2 += __shfl_xor(a2, off);
    }
    if (lane == 0) { sRed[8 + wave] = a0; sRed[12 + wave] = a1; sRed[16 + wave] = a2; }
    __syncthreads();
    if (tid < 128) {
        const float m0 = sRed[8] + sRed[9] + sRed[10] + sRed[11];
        const float m1 = sRed[12] + sRed[13] + sRed[14] + sRed[15];
        const float m2 = sRed[16] + sRed[17] + sRed[18] + sRed[19];
        const float w0 = Wpos[tid * 3 + 0], w1 = Wpos[tid * 3 + 1], w2 = Wpos[tid * 3 + 2];
        pfe_bf[(size_t)row * K_ + tid] = f2bf((m0 * w0 + m1 * w1 + m2 * w2) * inv);
    }
}

// ---------------------------------------------------------------------------
// Fused fat kernel (R15 — prep_sin eliminated, 3 kernels -> 2):
//   blocks [0,768)        edge rows (W1/W2 converted inline; padout here)
//   blocks [768,1152)     time-MLP layer 1 (sin features synthesized inline)
//   blocks [1152,2432)    Wpfe/Wproj/Wt2 f32->bf16 conversion for ts2_pe
//                         (backfills edge's idle HBM bandwidth)
// ---------------------------------------------------------------------------
__global__ __launch_bounds__(256, 3) void edge_ts1(
    const int* __restrict__ token_id,
    const unsigned char* __restrict__ is_periodic,
    const float* __restrict__ pos,
    const unsigned char* __restrict__ adj,
    const int* __restrict__ nte,
    const float* __restrict__ gbf_means,
    const float* __restrict__ gbf_stds,
    const float* __restrict__ gbf_mul,
    const float* __restrict__ gbf_bias,
    const float* __restrict__ b1,
    const float* __restrict__ b2,
    const float* __restrict__ Wpos,
    const float* __restrict__ W1,
    const float* __restrict__ W2,
    unsigned short* __restrict__ pfe_bf,
    unsigned short* __restrict__ ef_bf,
    float* __restrict__ out_pab,
    float* __restrict__ out_pad,
    const float* __restrict__ time_step,
    const unsigned char* __restrict__ clean_mask,
    const float* __restrict__ Wt1,
    const float* __restrict__ bt1,
    unsigned short* __restrict__ h1_bf,
    const float* __restrict__ Wpfe,
    const float* __restrict__ Wproj,
    const float* __restrict__ Wt2,
    unsigned short* __restrict__ Wpfebf,
    unsigned short* __restrict__ Wprojbf,
    unsigned short* __restrict__ Wt2bf)
{
    __shared__ __align__(16) char smem[34816];
    const int bx = blockIdx.x;
    if (bx < B_ * L_) {
        edge_body(smem, bx, token_id, is_periodic, pos, adj, nte,
                  gbf_means, gbf_stds, gbf_mul, gbf_bias, b1, b2, Wpos,
                  W1, W2, pfe_bf, ef_bf, out_pab, out_pad);
    } else if (bx < B_ * L_ + 384) {
        const int tsb = bx - B_ * L_;          // [0,384): 24 m-blocks x 16 n-blocks
        const int m0 = (tsb >> 4) * 32;
        const int n0 = (tsb & 15) * 64;
        gemm_ts_body(smem, m0, n0, time_step, clean_mask, Wt1, bt1, h1_bf, D_, D_);
    } else {
        // weight conversion for ts2_pe: 1280 blocks x 256 float4s
        const int i = (bx - (B_ * L_ + 384)) * 256 + threadIdx.x;  // [0,327680)
        const float* src; unsigned short* dst; int off;
        if (i < 32768)      { src = Wpfe;  dst = Wpfebf;  off = i; }
        else if (i < 65536) { src = Wproj; dst = Wprojbf; off = i - 32768; }
        else                { src = Wt2;   dst = Wt2bf;   off = i - 65536; }
        const float4 v = ((const float4*)src)[off];
        ushort4 p; p.x = f2bf(v.x); p.y = f2bf(v.y); p.z = f2bf(v.z); p.w = f2bf(v.w);
        ((ushort4*)dst)[off] = p;
    }
}

// ---------------------------------------------------------------------------
// Fused ts2 + pe_gemm + combine — EXACT R14 version (grid (32,24), BN=32,
// 3 blocks/CU; measured ≈ baseline-neutral).
// smem: phase1 sA[32][72]@0 + sB[32][72]@4608 = 9216 B;
// phase2 sA2[32][136]@0 + sB2[32][136]@8704 = 17408 B.
// ---------------------------------------------------------------------------
__global__ __launch_bounds__(256) void ts2_pe_kernel(
    const unsigned short* __restrict__ h1_bf,
    const unsigned short* __restrict__ Wt2bf,
    const float* __restrict__ bt2,
    const unsigned short* __restrict__ pfe_bf,
    const unsigned short* __restrict__ ef_bf,
    const unsigned short* __restrict__ Wpfebf,
    const unsigned short* __restrict__ Wprojbf,
    const float* __restrict__ bproj,
    const int* __restrict__ token,
    const float* __restrict__ embed_w,
    float* __restrict__ outTE,
    float* __restrict__ outPE,
    float* __restrict__ outX)
{
    __shared__ __align__(16) char smem[17408];
    const int tid  = threadIdx.x;
    const int lane = tid & 63;
    const int wave = tid >> 6;
    const int l15  = lane & 15;
    const int quad = lane >> 4;
    const int mt   = wave & 1;
    const int np   = wave >> 1;      // 0..1: 16-col half of the 32-col tile
    const int m0 = blockIdx.y * 32, n0 = blockIdx.x * 32;

    // ---- phase 1: te accumulation (K=1024, BK=64, all-bf16, reg prefetch)
    f32x4 accTE = (f32x4){0.f, 0.f, 0.f, 0.f};
    {
        unsigned short (*sA)[72] = (unsigned short(*)[72])smem;
        unsigned short (*sB)[72] = (unsigned short(*)[72])(smem + 4608);
        const int ar = tid >> 3, ac = (tid & 7) * 8;   // 32 rows x 64 cols

        uint4 ra = *(const uint4*)&h1_bf[(size_t)(m0 + ar) * D_ + ac];
        uint4 rb = *(const uint4*)&Wt2bf[(size_t)(n0 + ar) * D_ + ac];

        for (int k0 = 0; k0 < D_; k0 += 64) {
            *(uint4*)&sA[ar][ac] = ra;
            *(uint4*)&sB[ar][ac] = rb;
            __syncthreads();
            if (k0 + 64 < D_) {
                ra = *(const uint4*)&h1_bf[(size_t)(m0 + ar) * D_ + k0 + 64 + ac];
                rb = *(const uint4*)&Wt2bf[(size_t)(n0 + ar) * D_ + k0 + 64 + ac];
            }
#pragma unroll
            for (int kk = 0; kk < 64; kk += 32) {
                const bf16x8 av = *(const bf16x8*)&sA[mt * 16 + l15][kk + quad * 8];
                const bf16x8 bv = *(const bf16x8*)&sB[np * 16 + l15][kk + quad * 8];
                accTE = __builtin_amdgcn_mfma_f32_16x16x32_bf16(av, bv, accTE, 0, 0, 0);
            }
            __syncthreads();
        }
    }

    // ---- phase 2: pe accumulation (two K=128 passes, all-bf16)
    unsigned short (*sA2)[136] = (unsigned short(*)[136])smem;
    unsigned short (*sB2)[136] = (unsigned short(*)[136])(smem + 8704);
    f32x4 accPE = (f32x4){0.f, 0.f, 0.f, 0.f};

    for (int phase = 0; phase < 2; ++phase) {
        const unsigned short* Ap = phase ? ef_bf : pfe_bf;       // (768,128)
        const unsigned short* Bp = phase ? Wprojbf : Wpfebf;     // (1024,128)
#pragma unroll
        for (int e = tid; e < 512; e += 256) {
            const int r = e >> 4, c8 = (e & 15) * 8;
            *(uint4*)&sA2[r][c8] = *(const uint4*)&Ap[(size_t)(m0 + r) * K_ + c8];
        }
#pragma unroll
        for (int e = tid; e < 512; e += 256) {
            const int r = e >> 4, c8 = (e & 15) * 8;
            *(uint4*)&sB2[r][c8] = *(const uint4*)&Bp[(size_t)(n0 + r) * K_ + c8];
        }
        __syncthreads();
#pragma unroll
        for (int ks = 0; ks < 4; ++ks) {
            const bf16x8 av = *(const bf16x8*)&sA2[mt * 16 + l15][ks * 32 + quad * 8];
            const bf16x8 bv = *(const bf16x8*)&sB2[np * 16 + l15][ks * 32 + quad * 8];
            accPE = __builtin_amdgcn_mfma_f32_16x16x32_bf16(av, bv, accPE, 0, 0, 0);
        }
        __syncthreads();
    }

    // ---- epilogue: te, pe, x
    {
        const int nc = n0 + np * 16 + l15;
        const float bte = bt2[nc];
        const float bpe = bproj[nc];
#pragma unroll
        for (int r = 0; r < 4; ++r) {
            const int mr = m0 + mt * 16 + quad * 4 + r;
            const int tok = token[mr];
            const float te = accTE[r] + bte;
            const float pe = (tok == 0) ? 0.0f : (accPE[r] + bpe);
            outTE[(size_t)mr * D_ + nc] = te;
            outPE[(size_t)mr * D_ + nc] = pe;
            outX[(size_t)mr * D_ + nc] = embed_w[(size_t)tok * D_ + nc] + te + pe;
        }
    }
}

// ---------------------------------------------------------------------------
extern "C" void kernel_launch(void* const* d_in, const int* in_sizes, int n_in,
                              void* d_out, int out_size, void* d_ws, size_t ws_size,
                              hipStream_t stream) {
    const int*           token_id    = (const int*)d_in[0];
    const unsigned char* is_periodic = (const unsigned char*)d_in[1];
    const float*         pos         = (const float*)d_in[2];
    const unsigned char* adj         = (const unsigned char*)d_in[3];
    const int*           nte         = (const int*)d_in[4];
    const float*         time_step   = (const float*)d_in[5];
    const unsigned char* clean_mask  = (const unsigned char*)d_in[6];
    const float*         embed_w     = (const float*)d_in[7];
    const float*         Wpos        = (const float*)d_in[8];
    const float*         Wpfe        = (const float*)d_in[9];
    const float*         gbf_means   = (const float*)d_in[10];
    const float*         gbf_stds    = (const float*)d_in[11];
    const float*         gbf_mul     = (const float*)d_in[12];
    const float*         gbf_bias    = (const float*)d_in[13];
    const float*         W1          = (const float*)d_in[14];
    const float*         b1          = (const float*)d_in[15];
    const float*         W2          = (const float*)d_in[16];
    const float*         b2          = (const float*)d_in[17];
    const float*         Wproj       = (const float*)d_in[18];
    const float*         bproj       = (const float*)d_in[19];
    const float*         Wt1         = (const float*)d_in[20];
    const float*         bt1         = (const float*)d_in[21];
    const float*         Wt2         = (const float*)d_in[22];
    const float*         bt2         = (const float*)d_in[23];

    float* out = (float*)d_out;
    float* out_x   = out;                 // (B,L,D)
    float* out_pad = out + 786432;        // (B,L)
    float* out_te  = out + 787200;        // (B,L,D)
    float* out_pab = out + 1573632;       // (B,H,L,L)
    float* out_pe  = out + 11010816;      // (B,L,D)

    // workspace (ushort units)
    unsigned short* wsu = (unsigned short*)d_ws;
    unsigned short* Wpfebf  = wsu + 20480;         // 131072
    unsigned short* Wprojbf = wsu + 151552;        // 131072
    unsigned short* Wt2bf   = wsu + 282624;        // 1048576
    unsigned short* h1_bf   = wsu + 2117632;       // 786432
    unsigned short* pfe_bf  = wsu + 2904064;       // 98304
    unsigned short* ef_bf   = wsu + 3002368;       // 98304

    edge_ts1<<<dim3(B_ * L_ + 384 + 1280), dim3(256), 0, stream>>>(
        token_id, is_periodic, pos, adj, nte, gbf_means, gbf_stds, gbf_mul, gbf_bias,
        b1, b2, Wpos, W1, W2, pfe_bf, ef_bf, out_pab, out_pad,
        time_step, clean_mask, Wt1, bt1, h1_bf,
        Wpfe, Wproj, Wt2, Wpfebf, Wprojbf, Wt2bf);
    ts2_pe_kernel<<<dim3(32, 24), dim3(256), 0, stream>>>(
        h1_bf, Wt2bf, bt2, pfe_bf, ef_bf, Wpfebf, Wprojbf, bproj, token_id, embed_w,
        out_te, out_pe, out_x);
}